// Round 9
// baseline (122.594 us; speedup 1.0000x reference)
//
#include <hip/hip_runtime.h>

using u16 = unsigned short;
using u32 = unsigned int;

typedef __attribute__((ext_vector_type(8)))  short s16x8;
typedef __attribute__((ext_vector_type(4)))  float f32x4;
typedef __attribute__((ext_vector_type(16))) float f32x16;
typedef __attribute__((ext_vector_type(4)))  u32   u32x4;
typedef __attribute__((ext_vector_type(2)))  u32   u32x2;

#define NQ  74       // K chunks of 32 (2368 padded features)
#define NQQ 72       // quad chunks (column-major jr blocks); 72,73 = linear
#define WG_U16   (NQ * 8192)         // 606208 bf16 weights
#define RUNPK_OFF (WG_U16 * 2)       // byte offset of runpk[] in d_ws

__device__ __forceinline__ u16 f2bf_rne(float f) {
    u32 u = __builtin_bit_cast(u32, f);
    u32 r = u + 0x7fffu + ((u >> 16) & 1u);
    return (u16)(r >> 16);
}
__device__ __forceinline__ float bf2f(u16 u) {
    u32 v = ((u32)u) << 16;
    return __builtin_bit_cast(float, v);
}

// Column-major run schedule. Global run r (0..295):
//  r < 288: quad. chunk c=r>>2 lies in jr-block [jr(jr+1), (jr+1)(jr+2));
//           i = 4*(c - jr(jr+1)) + (r&3), j0 = 8*jr.  (j<i elems zero-padded)
//  r >= 288: linear (i = "ones"), j0 = 8*(r-288).
__device__ __forceinline__ void cm_decode(int r, int& i, int& j0) {
    if (r >= 288) { i = 64; j0 = (r - 288) * 8; return; }
    int c = r >> 2;
    int jr = 0;
    while (jr < 7 && (jr + 1) * (jr + 2) <= c) ++jr;
    i  = 4 * (c - jr * (jr + 1)) + (r & 3);
    j0 = 8 * jr;
}

// fc_w [256][2144] f32 -> wg bf16, flat idx
//   g = q*8192 + nc2*2048 + s*1024 + ni*512 + l*8 + e   (u16 units)
// out-row n = nc2*64 + ni*32 + (l&31); run = q*4 + 2s + (l>>5); elem e.
__global__ __launch_bounds__(1024)
void pack_w(const float* __restrict__ fcw, u16* __restrict__ wg,
            u32* __restrict__ runpk) {
    const u32 g = blockIdx.x * 1024 + threadIdx.x;
    if (blockIdx.x == 0 && threadIdx.x < NQQ) {
        int q = threadIdx.x, jr = 0;
        while (jr < 7 && (jr + 1) * (jr + 2) <= q) ++jr;
        runpk[q] = ((u32)(8 * jr) << 8) | (u32)(4 * (q - jr * (jr + 1)));
    }
    const int e   = g & 7;
    const int l   = (g >> 3) & 63;
    const int kh  = l >> 5;
    const int ni  = (g >> 9) & 1, s = (g >> 10) & 1;
    const int nc2 = (g >> 11) & 3;
    const int q   = g >> 13;
    int i, j0; cm_decode(q * 4 + 2 * s + kh, i, j0);
    const int n = nc2 * 64 + ni * 32 + (l & 31);
    const int j = j0 + e;
    float w;
    if (i == 64)    w = fcw[n * 2144 + j];                                     // linear
    else if (j < i) w = 0.f;                                                   // pad
    else            w = fcw[n * 2144 + 64 + i * 64 - ((i * (i - 1)) >> 1) + (j - i)];
    wg[g] = f2bf_rne(w);
}

// y[e] = fi * x[j0+e], f32 mul + truncating bf16 pack (proven R1-R8)
__device__ __forceinline__ s16x8 packmul(float fi, s16x8 vj) {
    u32 pk[4];
    #pragma unroll
    for (int d = 0; d < 4; ++d) {
        float p0 = fi * bf2f((u16)vj[2 * d]);
        float p1 = fi * bf2f((u16)vj[2 * d + 1]);
        pk[d] = __builtin_amdgcn_perm(__builtin_bit_cast(u32, p1),
                                      __builtin_bit_cast(u32, p0), 0x07060302u);
    }
    u32x4 pv = { pk[0], pk[1], pk[2], pk[3] };
    return __builtin_bit_cast(s16x8, pv);
}

__global__ __launch_bounds__(1024, 4)
void quad_gemm(const float* __restrict__ x, const u16* __restrict__ wg,
               const u32* __restrict__ runpk, float* __restrict__ out) {
    __shared__ __align__(16) u16 xl[128 * 64];     // bf16 [px][c ^ ((px&7)<<3)]
    __shared__ __align__(16) u16 wbuf[2][8192];    // double-buffered W chunk (16KB)
    __shared__ u32 runl[NQQ];

    const int t   = threadIdx.x;
    const int l   = t & 63;
    const int wv  = t >> 6;            // 16 waves: 4 mrow x 4 nc2
    const int mrow = wv >> 2, nc2 = wv & 3;
    const int lm  = l & 31, kh = l >> 5;
    const int sw  = (lm & 7) << 3;

    const int pix0 = (int)blockIdx.x * 128;
    const int b    = pix0 >> 12;
    const int hw0  = pix0 & 4095;

    if (t < NQQ) runl[t] = runpk[t];

    // ---- stage x tile (128 px x 64 ch), f32 -> bf16, XOR-swizzled
    {
        const int mg = (t & 31) * 4;          // 4 consecutive pixels
        const int cp = (t >> 5) * 2;          // 2 consecutive channels
        const float* xp = x + ((size_t)b << 18) + (size_t)cp * 4096 + hw0 + mg;
        f32x4 v0 = *(const f32x4*)(xp);
        f32x4 v1 = *(const f32x4*)(xp + 4096);
        #pragma unroll
        for (int r = 0; r < 4; ++r) {
            int m = mg + r;
            u32 pv = (u32)f2bf_rne(v0[r]) | ((u32)f2bf_rne(v1[r]) << 16);
            *(u32*)(xl + m * 64 + (cp ^ ((m & 7) << 3))) = pv;
        }
    }

    const int xrow  = (mrow * 32 + lm) << 6;
    const int wboff = nc2 * 2048 + l * 8;          // u16 units into a W chunk
    const u16* wsrc = wg + (size_t)t * 8;

    #define STAGEQ(Q, DSTP) __builtin_amdgcn_global_load_lds(                \
        (const __attribute__((address_space(1))) void*)(wsrc + (size_t)(Q) * 8192), \
        (__attribute__((address_space(3))) void*)((char*)(DSTP) + t * 16), 16, 0, 0)

    // W frags (W[s*2+ni]) from LDS chunk buffer
    #define LOADWF(SRC, W) do {                                              \
        const u16* bp_ = (SRC) + wboff;                                      \
        W[0] = *(const u32x4*)(bp_);                                         \
        W[1] = *(const u32x4*)(bp_ + 512);                                   \
        W[2] = *(const u32x4*)(bp_ + 1024);                                  \
        W[3] = *(const u32x4*)(bp_ + 1536);                                  \
    } while (0)

    // Y frags (Y[s]) for chunk Q from resident xl
    #define GENQ(Q, Y) do {                                                  \
        if ((Q) < NQQ) {                                                     \
            u32 meta_ = runl[(Q)];                                           \
            int j0_ = (int)((meta_ >> 8) & 255u), ib_ = (int)(meta_ & 255u); \
            s16x8 vj_ = *(const s16x8*)(xl + xrow + (j0_ ^ sw));             \
            u32x2 fq_ = *(const u32x2*)(xl + xrow + (ib_ ^ sw));             \
            _Pragma("unroll")                                                \
            for (int s_ = 0; s_ < 2; ++s_) {                                 \
                u32 fw_ = fq_[s_];                                           \
                u32 fb_ = kh ? (fw_ & 0xffff0000u) : (fw_ << 16);            \
                Y[s_] = packmul(__builtin_bit_cast(float, fb_), vj_);        \
            }                                                                \
        } else {                                                             \
            int cb_ = ((Q) - NQQ) * 32;                                      \
            _Pragma("unroll")                                                \
            for (int s_ = 0; s_ < 2; ++s_) {                                 \
                int j0_ = cb_ + 8 * (2 * s_ + kh);                           \
                Y[s_] = *(const s16x8*)(xl + xrow + (j0_ ^ sw));             \
            }                                                                \
        }                                                                    \
    } while (0)

    #define MFMAQ(W, Y) do {                                                 \
        _Pragma("unroll")                                                    \
        for (int s_ = 0; s_ < 2; ++s_)                                       \
            _Pragma("unroll")                                                \
            for (int ni_ = 0; ni_ < 2; ++ni_)                                \
                acc[ni_] = __builtin_amdgcn_mfma_f32_32x32x16_bf16(          \
                    __builtin_bit_cast(s16x8, W[s_ * 2 + ni_]),              \
                    Y[s_], acc[ni_], 0, 0, 0);                               \
    } while (0)

    #define FENCE asm volatile("" ::: "memory")

    f32x16 acc[2];
    #pragma unroll
    for (int ni = 0; ni < 2; ++ni)
        #pragma unroll
        for (int r = 0; r < 16; ++r) acc[ni][r] = 0.f;

    u16* wc = &wbuf[0][0];
    u16* wn = &wbuf[1][0];
    u32x4 Wf[4];
    s16x8 Ya[2], Yb[2];

    STAGEQ(0, wc);
    STAGEQ(1, wn);
    __syncthreads();               // xl + runl ready; stages 0,1 drained too
    GENQ(0, Ya);

    #pragma unroll 1
    for (int q = 0; q < 72; q += 2) {
        // ---- chunk q (in wc)
        asm volatile("s_waitcnt vmcnt(1)" ::: "memory");
        __builtin_amdgcn_s_barrier(); FENCE;
        LOADWF(wc, Wf);
        GENQ(q + 1, Yb);
        MFMAQ(Wf, Ya);
        FENCE; __builtin_amdgcn_s_barrier(); FENCE;
        STAGEQ(q + 2, wc);
        // ---- chunk q+1 (in wn)
        asm volatile("s_waitcnt vmcnt(1)" ::: "memory");
        __builtin_amdgcn_s_barrier(); FENCE;
        LOADWF(wn, Wf);
        GENQ(q + 2, Ya);
        MFMAQ(Wf, Yb);
        FENCE; __builtin_amdgcn_s_barrier(); FENCE;
        STAGEQ(q + 3, wn);
    }
    // ---- chunk 72 (wc): Ya holds it
    asm volatile("s_waitcnt vmcnt(1)" ::: "memory");
    __builtin_amdgcn_s_barrier(); FENCE;
    LOADWF(wc, Wf);
    GENQ(73, Yb);
    MFMAQ(Wf, Ya);
    // ---- chunk 73 (wn)
    asm volatile("s_waitcnt vmcnt(0)" ::: "memory");
    __builtin_amdgcn_s_barrier(); FENCE;
    LOADWF(wn, Wf);
    MFMAQ(Wf, Yb);

    // D: col = lane&31 -> pixel; row = (r&3) + 8*(r>>2) + 4*kh -> out channel
    float* ob = out + ((size_t)b << 20) + (size_t)hw0;
    const int px = mrow * 32 + lm;
    #pragma unroll
    for (int ni = 0; ni < 2; ++ni) {
        #pragma unroll
        for (int r = 0; r < 16; ++r) {
            const int o = nc2 * 64 + ni * 32 + 4 * kh + (r & 3) + 8 * (r >> 2);
            ob[(size_t)o * 4096 + px] = acc[ni][r];
        }
    }
}

extern "C" void kernel_launch(void* const* d_in, const int* in_sizes, int n_in,
                              void* d_out, int out_size, void* d_ws, size_t ws_size,
                              hipStream_t stream) {
    const float* x   = (const float*)d_in[0];
    const float* fcw = (const float*)d_in[1];
    float* out = (float*)d_out;
    u16* wg    = (u16*)d_ws;                              // 1.21 MB
    u32* runpk = (u32*)((char*)d_ws + RUNPK_OFF);         // 288 B

    hipLaunchKernelGGL(pack_w, dim3(WG_U16 / 1024), dim3(1024), 0, stream,
                       fcw, wg, runpk);
    hipLaunchKernelGGL(quad_gemm, dim3(256), dim3(1024), 0, stream,
                       x, wg, runpk, out);
}